// Round 1
// baseline (1315.373 us; speedup 1.0000x reference)
//
#include <hip/hip_runtime.h>
#include <hip/hip_bf16.h>

#define NSEQ 49
#define DIMC 192
#define NHEAD 6
#define HD 32
#define NWIN 1024
#define NBLK 8192
#define QSCALE 0.17677669529663687f

typedef __bf16 bf16x8 __attribute__((ext_vector_type(8)));
typedef float f32x4 __attribute__((ext_vector_type(4)));
typedef unsigned short ushort4v __attribute__((ext_vector_type(4)));

// workspace byte offsets
#define WQ_OFF 0          // bf16 [576][192]   221184 B  (q rows pre-scaled)
#define WP_OFF 221184     // bf16 [192][192]   73728 B
#define BIAS_OFF 294912   // f32  [6][49][49]  57624 B
#define QB_OFF 352544     // f32  [576]        (q part pre-scaled)
#define PB_OFF 354848     // f32  [192]

__device__ __forceinline__ unsigned short f2bf(float f) {
  unsigned int u = __builtin_bit_cast(unsigned int, f);
  u += 0x7fffu + ((u >> 16) & 1u);   // RNE
  return (unsigned short)(u >> 16);
}

__device__ __forceinline__ f32x4 mfma16(bf16x8 a, bf16x8 b, f32x4 c) {
  return __builtin_amdgcn_mfma_f32_16x16x32_bf16(a, b, c, 0, 0, 0);
}

__global__ void prep_kernel(const float* __restrict__ qkv_w, const float* __restrict__ qkv_b,
                            const float* __restrict__ proj_w, const float* __restrict__ proj_b,
                            const float* __restrict__ table, const int* __restrict__ ridx,
                            char* __restrict__ ws) {
  unsigned short* wq = (unsigned short*)(ws + WQ_OFF);
  unsigned short* wp = (unsigned short*)(ws + WP_OFF);
  float* biasf = (float*)(ws + BIAS_OFF);
  float* qb = (float*)(ws + QB_OFF);
  float* pb = (float*)(ws + PB_OFF);
  int idx = blockIdx.x * blockDim.x + threadIdx.x;
  const int T0 = 576*192, T1 = T0 + 192*192, T2 = T1 + NHEAD*NSEQ*NSEQ, T3 = T2 + 576, T4 = T3 + 192;
  if (idx < T0) {
    float f = qkv_w[idx];
    if (idx < 192*192) f *= QSCALE;      // fold q scale into Wq
    wq[idx] = f2bf(f);
  } else if (idx < T1) {
    int i = idx - T0;
    wp[i] = f2bf(proj_w[i]);
  } else if (idx < T2) {
    int i = idx - T1;
    int h = i / (NSEQ*NSEQ), rc = i - h*(NSEQ*NSEQ);
    biasf[i] = table[ridx[rc]*NHEAD + h];
  } else if (idx < T3) {
    int i = idx - T2;
    qb[i] = qkv_b[i] * (i < 192 ? QSCALE : 1.0f);
  } else if (idx < T4) {
    int i = idx - T3;
    pb[i] = proj_b[i];
  }
}

// LDS layout (bytes), total 130816 (< 128KiB known-good envelope):
//   [0, 25600)      xs  bf16 [64][200]      } union: xs dead after GEMM1,
//   [0, 16896)      S   f32  [64][66]       }  S/P live per-head after
//   [16896, 26112)  P   bf16 [64][72]       }
//   [26112, 51712)  qs  bf16 [64][200]
//   [51712, 77312)  ks  bf16 [64][200]
//   [77312, 104960) vs  bf16 [192][72]   (v transposed: [h*32+d][seq])
//   [104960,130560) os  bf16 [64][200]
//   [130560,130816) rsum f32 [64]
__global__ __launch_bounds__(512)
void wattn_kernel(const float* __restrict__ x, const float* __restrict__ mask,
                  const char* __restrict__ ws, float* __restrict__ out) {
  __shared__ __align__(16) char smem[130816];
  unsigned short* xs = (unsigned short*)smem;
  float* S = (float*)smem;
  unsigned short* P  = (unsigned short*)(smem + 16896);
  unsigned short* qs = (unsigned short*)(smem + 26112);
  unsigned short* ks = (unsigned short*)(smem + 51712);
  unsigned short* vs = (unsigned short*)(smem + 77312);
  unsigned short* os = (unsigned short*)(smem + 104960);
  float* rsum = (float*)(smem + 130560);

  const unsigned short* wq = (const unsigned short*)(ws + WQ_OFF);
  const unsigned short* wp = (const unsigned short*)(ws + WP_OFF);
  const float* biasf = (const float*)(ws + BIAS_OFF);
  const float* qb = (const float*)(ws + QB_OFF);
  const float* pb = (const float*)(ws + PB_OFF);

  const int tid = threadIdx.x;
  const int wave = tid >> 6, lane = tid & 63;
  const int lhi = lane >> 4, llo = lane & 15;
  const int win = blockIdx.x;

  // ---- phase A: x -> xs (bf16), rows 49..63 zero ----
  {
    const float* xp = x + (size_t)win * (NSEQ*DIMC);
    for (int idx = tid; idx < 64*48; idx += 512) {
      int r = idx / 48, c4 = idx - r*48;
      float4 f = make_float4(0.f, 0.f, 0.f, 0.f);
      if (r < NSEQ) f = *(const float4*)(xp + r*DIMC + c4*4);
      ushort4v u = { f2bf(f.x), f2bf(f.y), f2bf(f.z), f2bf(f.w) };
      *(ushort4v*)(xs + r*200 + c4*4) = u;
    }
  }
  __syncthreads();

  // ---- GEMM1: qkv[64][576] = xs @ Wqkv^T + b; route to qs/ks/vs ----
  for (int s = wave; s < 36; s += 8) {
    const unsigned short* wrow = wq + (s*16 + llo)*DIMC + lhi*8;
    bf16x8 b0 = *(const bf16x8*)(wrow +   0);
    bf16x8 b1 = *(const bf16x8*)(wrow +  32);
    bf16x8 b2 = *(const bf16x8*)(wrow +  64);
    bf16x8 b3 = *(const bf16x8*)(wrow +  96);
    bf16x8 b4 = *(const bf16x8*)(wrow + 128);
    bf16x8 b5 = *(const bf16x8*)(wrow + 160);
    f32x4 acc[4];
    #pragma unroll
    for (int rt = 0; rt < 4; ++rt) {
      const unsigned short* ar = xs + (rt*16 + llo)*200 + lhi*8;
      f32x4 a = {0.f, 0.f, 0.f, 0.f};
      a = mfma16(*(const bf16x8*)(ar +   0), b0, a);
      a = mfma16(*(const bf16x8*)(ar +  32), b1, a);
      a = mfma16(*(const bf16x8*)(ar +  64), b2, a);
      a = mfma16(*(const bf16x8*)(ar +  96), b3, a);
      a = mfma16(*(const bf16x8*)(ar + 128), b4, a);
      a = mfma16(*(const bf16x8*)(ar + 160), b5, a);
      acc[rt] = a;
    }
    float bn = qb[s*16 + llo];
    #pragma unroll
    for (int rt = 0; rt < 4; ++rt) {
      #pragma unroll
      for (int i = 0; i < 4; ++i) {
        int row = rt*16 + lhi*4 + i;
        unsigned short hv = f2bf(acc[rt][i] + bn);
        if (s < 12)      qs[row*200 + s*16 + llo] = hv;
        else if (s < 24) ks[row*200 + (s-12)*16 + llo] = hv;
        else             vs[((s-24)*16 + llo)*72 + row] = hv;  // transposed
      }
    }
  }
  __syncthreads();

  const float* mrow = mask + (size_t)(win & (NWIN-1)) * (NSEQ*NSEQ);
  for (int h = 0; h < NHEAD; ++h) {
    // ---- QK^T (+bias+mask) -> S (f32); pad cols forced to -1e30 ----
    #pragma unroll
    for (int tt = 0; tt < 2; ++tt) {
      int t = wave*2 + tt;
      int ti = t >> 2, tj = t & 3;
      bf16x8 a = *(const bf16x8*)(qs + (ti*16 + llo)*200 + h*HD + lhi*8);
      bf16x8 b = *(const bf16x8*)(ks + (tj*16 + llo)*200 + h*HD + lhi*8);
      f32x4 acc = {0.f, 0.f, 0.f, 0.f};
      acc = mfma16(a, b, acc);
      int col = tj*16 + llo;
      const float* brow = biasf + h*(NSEQ*NSEQ);
      #pragma unroll
      for (int i = 0; i < 4; ++i) {
        int row = ti*16 + lhi*4 + i;
        float v;
        if (col < NSEQ) {
          v = acc[i];
          if (row < NSEQ) v += brow[row*NSEQ + col] + mrow[row*NSEQ + col];
        } else {
          v = -1e30f;
        }
        S[row*66 + col] = v;
      }
    }
    __syncthreads();
    // ---- softmax: 8 lanes per row, exp in f32, P bf16, keep 1/sum ----
    {
      int r = tid >> 3, sub = tid & 7;
      float* Sr = S + r*66;
      unsigned short* Pr = P + r*72;
      if (r < NSEQ) {
        float vals[8];
        float m = -1e30f;
        #pragma unroll
        for (int t = 0; t < 8; ++t) { vals[t] = Sr[sub + 8*t]; m = fmaxf(m, vals[t]); }
        m = fmaxf(m, __shfl_xor(m, 1));
        m = fmaxf(m, __shfl_xor(m, 2));
        m = fmaxf(m, __shfl_xor(m, 4));
        float sum = 0.f;
        #pragma unroll
        for (int t = 0; t < 8; ++t) {
          float e = __expf(vals[t] - m);   // pad cols: exp(-1e30-m) -> 0
          sum += e;
          Pr[sub + 8*t] = f2bf(e);
        }
        sum += __shfl_xor(sum, 1);
        sum += __shfl_xor(sum, 2);
        sum += __shfl_xor(sum, 4);
        if (sub == 0) rsum[r] = 1.f / sum;
      } else {
        #pragma unroll
        for (int t = 0; t < 8; ++t) Pr[sub + 8*t] = 0;
        if (sub == 0) rsum[r] = 0.f;
      }
    }
    __syncthreads();
    // ---- PV: os[.., h*32..] = (P @ V) * 1/sum ----
    {
      int rt = wave >> 1, ct = wave & 1;
      f32x4 acc = {0.f, 0.f, 0.f, 0.f};
      #pragma unroll
      for (int kk = 0; kk < 2; ++kk) {
        bf16x8 a = *(const bf16x8*)(P  + (rt*16 + llo)*72 + kk*32 + lhi*8);
        bf16x8 b = *(const bf16x8*)(vs + (h*HD + ct*16 + llo)*72 + kk*32 + lhi*8);
        acc = mfma16(a, b, acc);
      }
      #pragma unroll
      for (int i = 0; i < 4; ++i) {
        int row = rt*16 + lhi*4 + i;
        os[row*200 + h*HD + ct*16 + llo] = f2bf(acc[i] * rsum[row]);
      }
    }
    __syncthreads();
  }

  // ---- proj: out = os @ Wp^T + pb ----
  for (int s = wave; s < 12; s += 8) {
    const unsigned short* wrow = wp + (s*16 + llo)*DIMC + lhi*8;
    bf16x8 b0 = *(const bf16x8*)(wrow +   0);
    bf16x8 b1 = *(const bf16x8*)(wrow +  32);
    bf16x8 b2 = *(const bf16x8*)(wrow +  64);
    bf16x8 b3 = *(const bf16x8*)(wrow +  96);
    bf16x8 b4 = *(const bf16x8*)(wrow + 128);
    bf16x8 b5 = *(const bf16x8*)(wrow + 160);
    f32x4 acc[4];
    #pragma unroll
    for (int rt = 0; rt < 4; ++rt) {
      const unsigned short* ar = os + (rt*16 + llo)*200 + lhi*8;
      f32x4 a = {0.f, 0.f, 0.f, 0.f};
      a = mfma16(*(const bf16x8*)(ar +   0), b0, a);
      a = mfma16(*(const bf16x8*)(ar +  32), b1, a);
      a = mfma16(*(const bf16x8*)(ar +  64), b2, a);
      a = mfma16(*(const bf16x8*)(ar +  96), b3, a);
      a = mfma16(*(const bf16x8*)(ar + 128), b4, a);
      a = mfma16(*(const bf16x8*)(ar + 160), b5, a);
      acc[rt] = a;
    }
    float pbn = pb[s*16 + llo];
    #pragma unroll
    for (int rt = 0; rt < 4; ++rt) {
      #pragma unroll
      for (int i = 0; i < 4; ++i) {
        int row = rt*16 + lhi*4 + i;
        if (row < NSEQ)
          out[((size_t)win*NSEQ + row)*DIMC + s*16 + llo] = acc[rt][i] + pbn;
      }
    }
  }
}

extern "C" void kernel_launch(void* const* d_in, const int* in_sizes, int n_in,
                              void* d_out, int out_size, void* d_ws, size_t ws_size,
                              hipStream_t stream) {
  const float* x      = (const float*)d_in[0];
  const float* mask   = (const float*)d_in[1];
  const float* qkv_w  = (const float*)d_in[2];
  const float* qkv_b  = (const float*)d_in[3];
  const float* proj_w = (const float*)d_in[4];
  const float* proj_b = (const float*)d_in[5];
  const float* table  = (const float*)d_in[6];
  const int*   ridx   = (const int*)d_in[7];
  float* out = (float*)d_out;
  char* ws = (char*)d_ws;

  const int prep_total = 576*192 + 192*192 + NHEAD*NSEQ*NSEQ + 576 + 192;
  prep_kernel<<<(prep_total + 255)/256, 256, 0, stream>>>(qkv_w, qkv_b, proj_w, proj_b, table, ridx, ws);
  wattn_kernel<<<NBLK, 512, 0, stream>>>(x, mask, ws, out);
}

// Round 3
// 1103.495 us; speedup vs baseline: 1.1920x; 1.1920x over previous
//
#include <hip/hip_runtime.h>
#include <hip/hip_bf16.h>

#define NSEQ 49
#define DIMC 192
#define NHEAD 6
#define NWIN 1024
#define NBLK 8192
#define NN 2401      // 49*49
#define QSCALE 0.17677669529663687f

typedef __bf16 bf16x8 __attribute__((ext_vector_type(8)));
typedef float f32x4 __attribute__((ext_vector_type(4)));
typedef unsigned int u32x4 __attribute__((ext_vector_type(4)));
typedef unsigned short u16;

// workspace byte offsets
#define WQ_OFF 0          // bf16 [576][192]  (q rows pre-scaled)
#define WP_OFF 221184     // bf16 [192][192]
#define BIAS_OFF 294912   // f32  [6][49][49]
#define QB_OFF 352544     // f32  [576] (q part pre-scaled)
#define PB_OFF 354848     // f32  [192]

__device__ __forceinline__ u16 f2bf(float f) {
  unsigned int u = __builtin_bit_cast(unsigned int, f);
  u += 0x7fffu + ((u >> 16) & 1u);   // RNE
  return (u16)(u >> 16);
}
__device__ __forceinline__ f32x4 mfma16(bf16x8 a, bf16x8 b, f32x4 c) {
  return __builtin_amdgcn_mfma_f32_16x16x32_bf16(a, b, c, 0, 0, 0);
}
__device__ __forceinline__ f32x4 ld4u(const float* p) {   // 4B-aligned float4
  f32x4 v; __builtin_memcpy(&v, p, 16); return v;
}
__device__ __forceinline__ bf16x8 pack8(f32x4 a, f32x4 b) {
  u32x4 w;
  w[0] = f2bf(a[0]) | ((unsigned)f2bf(a[1]) << 16);
  w[1] = f2bf(a[2]) | ((unsigned)f2bf(a[3]) << 16);
  w[2] = f2bf(b[0]) | ((unsigned)f2bf(b[1]) << 16);
  w[3] = f2bf(b[2]) | ((unsigned)f2bf(b[3]) << 16);
  return __builtin_bit_cast(bf16x8, w);
}

__global__ void prep_kernel(const float* __restrict__ qkv_w, const float* __restrict__ qkv_b,
                            const float* __restrict__ proj_w, const float* __restrict__ proj_b,
                            const float* __restrict__ table, const int* __restrict__ ridx,
                            char* __restrict__ ws) {
  u16* wq = (u16*)(ws + WQ_OFF);
  u16* wp = (u16*)(ws + WP_OFF);
  float* biasf = (float*)(ws + BIAS_OFF);
  float* qb = (float*)(ws + QB_OFF);
  float* pb = (float*)(ws + PB_OFF);
  int idx = blockIdx.x * blockDim.x + threadIdx.x;
  const int T0 = 576*192, T1 = T0 + 192*192, T2 = T1 + NHEAD*NN, T3 = T2 + 576, T4 = T3 + 192;
  if (idx < T0) {
    float f = qkv_w[idx];
    if (idx < 192*192) f *= QSCALE;
    wq[idx] = f2bf(f);
  } else if (idx < T1) {
    int i = idx - T0;
    wp[i] = f2bf(proj_w[i]);
  } else if (idx < T2) {
    int i = idx - T1;
    int h = i / NN, rc = i - h*NN;
    biasf[i] = table[ridx[rc]*NHEAD + h];
  } else if (idx < T3) {
    int i = idx - T2;
    qb[i] = qkv_b[i] * (i < 192 ? QSCALE : 1.0f);
  } else if (idx < T4) {
    int i = idx - T3;
    pb[i] = proj_b[i];
  }
}

// LDS 73728 B total -> 2 blocks/CU.
//   qkb: [64 rows][384 u16] = q cols 0..191 (later aliased by O), k cols 192..383
//   vsb: [192 rows(dim)][64 u16(seq)]  (V transposed)
// Both XOR-swizzled: byte_in_row ^= (row&7)<<4
// Barrier discipline: every LDS write-phase -> read-phase handoff is ordered
// by __syncthreads (2 total). R2's barrier-free same-wave handoff diverged
// under graph replay.
__global__ __launch_bounds__(384, 2)
void wattn_kernel(const float* __restrict__ x, const float* __restrict__ mask,
                  const char* __restrict__ ws, float* __restrict__ out) {
  __shared__ __align__(16) char smem[73728];
  char* qkb = smem;
  char* vsb = smem + 49152;

  const u16* wq = (const u16*)(ws + WQ_OFF);
  const u16* wp = (const u16*)(ws + WP_OFF);
  const float* biasf = (const float*)(ws + BIAS_OFF);
  const float* qb = (const float*)(ws + QB_OFF);
  const float* pb = (const float*)(ws + PB_OFF);

  const int tid = threadIdx.x;
  const int wave = tid >> 6;        // 0..5 == head
  const int lane = tid & 63;
  const int lhi = lane >> 4, llo = lane & 15;
  const int win = blockIdx.x;
  const int h = wave;

  // ---- preload x as bf16 A-frags (rows 49..63 zero) ----
  bf16x8 xa[4][6];
  {
    const float* xp = x + (size_t)win * (NSEQ*DIMC);
    #pragma unroll
    for (int rt = 0; rt < 4; ++rt) {
      int row = rt*16 + llo;
      bool valid = (row < NSEQ);
      const float* pr = xp + row*DIMC + lhi*8;
      #pragma unroll
      for (int kk = 0; kk < 6; ++kk) {
        f32x4 f0 = {0.f,0.f,0.f,0.f}, f1 = {0.f,0.f,0.f,0.f};
        if (valid) { f0 = *(const f32x4*)(pr + kk*32); f1 = *(const f32x4*)(pr + kk*32 + 4); }
        xa[rt][kk] = pack8(f0, f1);
      }
    }
  }

  // ---- GEMM1: wave h computes its OWN head's q,k,v chunks ----
  #pragma unroll
  for (int cc = 0; cc < 6; ++cc) {
    int s = (cc < 2) ? (wave*2 + cc)
          : (cc < 4) ? (12 + wave*2 + (cc - 2))
                     : (24 + wave*2 + (cc - 4));
    const u16* wrow = wq + (s*16 + llo)*DIMC + lhi*8;
    bf16x8 b0 = *(const bf16x8*)(wrow +   0);
    bf16x8 b1 = *(const bf16x8*)(wrow +  32);
    bf16x8 b2 = *(const bf16x8*)(wrow +  64);
    bf16x8 b3 = *(const bf16x8*)(wrow +  96);
    bf16x8 b4 = *(const bf16x8*)(wrow + 128);
    bf16x8 b5 = *(const bf16x8*)(wrow + 160);
    float bn = qb[s*16 + llo];
    #pragma unroll
    for (int rt = 0; rt < 4; ++rt) {
      f32x4 acc = {0.f,0.f,0.f,0.f};
      acc = mfma16(xa[rt][0], b0, acc);
      acc = mfma16(xa[rt][1], b1, acc);
      acc = mfma16(xa[rt][2], b2, acc);
      acc = mfma16(xa[rt][3], b3, acc);
      acc = mfma16(xa[rt][4], b4, acc);
      acc = mfma16(xa[rt][5], b5, acc);
      if (cc < 4) {
        int col = s*16 + llo;          // q: 0..191, k: 192..383
        #pragma unroll
        for (int i = 0; i < 4; ++i) {
          int row = rt*16 + lhi*4 + i;
          *(u16*)(qkb + row*768 + ((col*2) ^ ((row&7)<<4))) = f2bf(acc[i] + bn);
        }
      } else {
        int d = (s - 24)*16 + llo;     // dim index 0..191
        #pragma unroll
        for (int i = 0; i < 4; ++i) {
          int seq = rt*16 + lhi*4 + i;
          *(u16*)(vsb + d*128 + ((seq*2) ^ ((d&7)<<4))) = f2bf(acc[i] + bn);
        }
      }
    }
  }

  __syncthreads();   // barrier 1: all q/k/v LDS writes ordered before any read

  // ---- QK^T swapped: T = K·Q^T (rows=key in (lhi,reg), cols=q in llo) ----
  bf16x8 kf[4], qf[4];
  #pragma unroll
  for (int tt = 0; tt < 4; ++tt) {
    int row = tt*16 + llo;
    kf[tt] = *(const bf16x8*)(qkb + row*768 + ((((192 + h*32)*2) + lhi*16) ^ ((row&7)<<4)));
    qf[tt] = *(const bf16x8*)(qkb + row*768 + ((((h*32)*2) + lhi*16) ^ ((row&7)<<4)));
  }
  f32x4 t[4][4];   // [kt][qt]
  #pragma unroll
  for (int kt = 0; kt < 4; ++kt)
    #pragma unroll
    for (int qt = 0; qt < 4; ++qt) {
      f32x4 z = {0.f,0.f,0.f,0.f};
      t[kt][qt] = mfma16(kf[kt], qf[qt], z);
    }

  // ---- + bias^T + mask^T (global, L2-hot) ----
  {
    const float* brow = biasf + h*NN;
    const float* mrow = mask + (size_t)(win & (NWIN-1))*NN;
    #pragma unroll
    for (int qt = 0; qt < 4; ++qt) {
      int q = qt*16 + llo;
      if (q < NSEQ) {
        #pragma unroll
        for (int kt = 0; kt < 3; ++kt) {
          int kb = kt*16 + lhi*4;
          f32x4 b4 = ld4u(brow + q*NSEQ + kb);
          f32x4 m4 = ld4u(mrow + q*NSEQ + kb);
          #pragma unroll
          for (int i = 0; i < 4; ++i) t[kt][qt][i] += b4[i] + m4[i];
        }
        if (lhi == 0) t[3][qt][0] += brow[q*NSEQ + 48] + mrow[q*NSEQ + 48];
      }
    }
  }

  // ---- softmax over keys: in-lane + shfl_xor over lhi ----
  unsigned int pk[4][4][2];   // [kt][qt][bf16-pair]
  #pragma unroll
  for (int qt = 0; qt < 4; ++qt) {
    float m = -1e30f;
    #pragma unroll
    for (int kt = 0; kt < 3; ++kt)
      #pragma unroll
      for (int i = 0; i < 4; ++i) m = fmaxf(m, t[kt][qt][i]);
    if (lhi == 0) m = fmaxf(m, t[3][qt][0]);
    m = fmaxf(m, __shfl_xor(m, 16));
    m = fmaxf(m, __shfl_xor(m, 32));
    float sum = 0.f;
    #pragma unroll
    for (int kt = 0; kt < 3; ++kt)
      #pragma unroll
      for (int i = 0; i < 4; ++i) { float e = __expf(t[kt][qt][i] - m); t[kt][qt][i] = e; sum += e; }
    { float e = (lhi == 0) ? __expf(t[3][qt][0] - m) : 0.f; t[3][qt][0] = e; sum += e; }
    t[3][qt][1] = 0.f; t[3][qt][2] = 0.f; t[3][qt][3] = 0.f;
    sum += __shfl_xor(sum, 16);
    sum += __shfl_xor(sum, 32);
    float inv = 1.f / sum;
    #pragma unroll
    for (int kt = 0; kt < 4; ++kt) {
      float p0 = t[kt][qt][0]*inv, p1 = t[kt][qt][1]*inv;
      float p2 = t[kt][qt][2]*inv, p3 = t[kt][qt][3]*inv;
      pk[kt][qt][0] = f2bf(p0) | ((unsigned)f2bf(p1) << 16);
      pk[kt][qt][1] = f2bf(p2) | ((unsigned)f2bf(p3) << 16);
    }
  }

  // ---- PV: O = P·V. P A-frags via shfl transpose; V b-frags from vsb ----
  f32x4 o[4][2];
  #pragma unroll
  for (int qt = 0; qt < 4; ++qt)
    #pragma unroll
    for (int dt = 0; dt < 2; ++dt) o[qt][dt] = (f32x4){0.f,0.f,0.f,0.f};
  #pragma unroll
  for (int kk = 0; kk < 2; ++kk) {
    bf16x8 pa[4];
    #pragma unroll
    for (int qt = 0; qt < 4; ++qt) {
      u32x4 w;
      #pragma unroll
      for (int ee = 0; ee < 4; ++ee) {
        int src = (((lhi & 1)*2 + (ee >> 1)) << 4) + llo;
        int wA = __shfl((int)pk[2*kk    ][qt][ee & 1], src);
        int wB = __shfl((int)pk[2*kk + 1][qt][ee & 1], src);
        w[ee] = (lhi < 2) ? (unsigned)wA : (unsigned)wB;
      }
      pa[qt] = __builtin_bit_cast(bf16x8, w);
    }
    #pragma unroll
    for (int dt = 0; dt < 2; ++dt) {
      int dg = h*32 + dt*16 + llo;
      bf16x8 vf = *(const bf16x8*)(vsb + dg*128 + ((kk*64 + lhi*16) ^ ((dg&7)<<4)));
      #pragma unroll
      for (int qt = 0; qt < 4; ++qt) o[qt][dt] = mfma16(pa[qt], vf, o[qt][dt]);
    }
  }

  // ---- write O into own dead q-columns (alias), bf16 ----
  #pragma unroll
  for (int qt = 0; qt < 4; ++qt)
    #pragma unroll
    for (int dt = 0; dt < 2; ++dt)
      #pragma unroll
      for (int i = 0; i < 4; ++i) {
        int row = qt*16 + lhi*4 + i;
        int col = h*32 + dt*16 + llo;
        *(u16*)(qkb + row*768 + ((col*2) ^ ((row&7)<<4))) = f2bf(o[qt][dt][i]);
      }

  __syncthreads();   // barrier 2: O complete across heads before proj

  // ---- proj: out = O @ Wp^T + pb ----
  #pragma unroll
  for (int ss = 0; ss < 2; ++ss) {
    int s = wave + ss*6;
    const u16* wrow = wp + (s*16 + llo)*DIMC + lhi*8;
    bf16x8 b0 = *(const bf16x8*)(wrow +   0);
    bf16x8 b1 = *(const bf16x8*)(wrow +  32);
    bf16x8 b2 = *(const bf16x8*)(wrow +  64);
    bf16x8 b3 = *(const bf16x8*)(wrow +  96);
    bf16x8 b4 = *(const bf16x8*)(wrow + 128);
    bf16x8 b5 = *(const bf16x8*)(wrow + 160);
    float bn = pb[s*16 + llo];
    #pragma unroll
    for (int rt = 0; rt < 4; ++rt) {
      int arow = rt*16 + llo;
      f32x4 acc = {0.f,0.f,0.f,0.f};
      acc = mfma16(*(const bf16x8*)(qkb + arow*768 + ((  0 + lhi*16) ^ ((arow&7)<<4))), b0, acc);
      acc = mfma16(*(const bf16x8*)(qkb + arow*768 + (( 64 + lhi*16) ^ ((arow&7)<<4))), b1, acc);
      acc = mfma16(*(const bf16x8*)(qkb + arow*768 + ((128 + lhi*16) ^ ((arow&7)<<4))), b2, acc);
      acc = mfma16(*(const bf16x8*)(qkb + arow*768 + ((192 + lhi*16) ^ ((arow&7)<<4))), b3, acc);
      acc = mfma16(*(const bf16x8*)(qkb + arow*768 + ((256 + lhi*16) ^ ((arow&7)<<4))), b4, acc);
      acc = mfma16(*(const bf16x8*)(qkb + arow*768 + ((320 + lhi*16) ^ ((arow&7)<<4))), b5, acc);
      #pragma unroll
      for (int i = 0; i < 4; ++i) {
        int row = rt*16 + lhi*4 + i;
        if (row < NSEQ)
          out[((size_t)win*NSEQ + row)*DIMC + s*16 + llo] = acc[i] + bn;
      }
    }
  }
}

extern "C" void kernel_launch(void* const* d_in, const int* in_sizes, int n_in,
                              void* d_out, int out_size, void* d_ws, size_t ws_size,
                              hipStream_t stream) {
  const float* x      = (const float*)d_in[0];
  const float* mask   = (const float*)d_in[1];
  const float* qkv_w  = (const float*)d_in[2];
  const float* qkv_b  = (const float*)d_in[3];
  const float* proj_w = (const float*)d_in[4];
  const float* proj_b = (const float*)d_in[5];
  const float* table  = (const float*)d_in[6];
  const int*   ridx   = (const int*)d_in[7];
  float* out = (float*)d_out;
  char* ws = (char*)d_ws;

  const int prep_total = 576*192 + 192*192 + NHEAD*NN + 576 + 192;
  prep_kernel<<<(prep_total + 255)/256, 256, 0, stream>>>(qkv_w, qkv_b, proj_w, proj_b, table, ridx, ws);
  wattn_kernel<<<NBLK, 384, 0, stream>>>(x, mask, ws, out);
}